// Round 1
// baseline (523.605 us; speedup 1.0000x reference)
//
#include <hip/hip_runtime.h>
#include <stdint.h>
#include <stddef.h>

// ---------- types / helpers ----------
typedef __attribute__((ext_vector_type(8))) short bf16x8;   // 8 bf16 in 4 VGPRs
typedef __attribute__((ext_vector_type(4))) float f32x4;

typedef __attribute__((address_space(1))) unsigned int uint_g;
typedef __attribute__((address_space(3))) unsigned int uint_l;

#define DEV static __device__ __forceinline__

DEV unsigned short f2bf(float f) {          // RNE float -> bf16 bits
  unsigned int u = __float_as_uint(f);
  u += 0x7FFFu + ((u >> 16) & 1u);
  return (unsigned short)(u >> 16);
}

DEV void gl_lds16(const unsigned short* g, unsigned short* l) {
  // async global->LDS, 16B per lane; LDS dest = wave-uniform base + lane*16
  __builtin_amdgcn_global_load_lds((const uint_g*)g, (uint_l*)l, 16, 0, 0);
}

// ---------- elementwise f32 -> bf16 (vectorized x4) ----------
__global__ __launch_bounds__(256) void k_f32_to_bf16(const float* __restrict__ in,
                                                     unsigned short* __restrict__ out, int n4) {
  int i = blockIdx.x * 256 + threadIdx.x;
  if (i >= n4) return;
  const float4 v = ((const float4*)in)[i];
  ushort4 o;
  o.x = f2bf(v.x); o.y = f2bf(v.y); o.z = f2bf(v.z); o.w = f2bf(v.w);
  ((ushort4*)out)[i] = o;
}

// ---------- transpose fp32 [R][C] -> bf16 [C][R] ----------
__global__ __launch_bounds__(256) void k_transpose_to_bf16(const float* __restrict__ in,
                                                           unsigned short* __restrict__ out,
                                                           int R, int C) {
  __shared__ unsigned short tile[32][33];   // +1 pad breaks bank conflicts
  const int c0 = blockIdx.x << 5, r0 = blockIdx.y << 5;
  const int tx = threadIdx.x & 31, ty = threadIdx.x >> 5;   // 32x8
  #pragma unroll
  for (int i = 0; i < 32; i += 8)
    tile[ty + i][tx] = f2bf(in[(size_t)(r0 + ty + i) * C + c0 + tx]);
  __syncthreads();
  #pragma unroll
  for (int i = 0; i < 32; i += 8)
    out[(size_t)(c0 + ty + i) * R + r0 + tx] = tile[tx][ty + i];
}

// ---------- generic bf16 MFMA GEMM: C = A @ B^T (+epilogue) ----------
// v3: same single-barrier double-buffered skeleton as v2, but big GEMMs now
// instantiate BM=256,BN=128 (per-wave 128x64, TM=8/TN=4): 32 MFMA per
// K-step/wave vs 12 ds_read_b128 -> per-step latency amortized over 2x FLOPs.
// __launch_bounds__(256,2) pins 2 blocks/CU (<=256 regs incl. 128 AGPR acc).
enum { EPI_BIAS = 0, EPI_VT = 3, EPI_DUAL = 4, EPI_RELU = 5, EPI_RES = 6 };

template <int BM, int BN, int EPI>
__global__ __launch_bounds__(256, 2)
void k_gemm(const unsigned short* __restrict__ A, const unsigned short* __restrict__ B,
            int lda, int ldb, int kSteps,
            void* C0, void* C1, const float* bias, const float* resid, int ldc, float scale) {
  constexpr int TM = BM / 32;
  constexpr int TN = BN / 32;
  __shared__ unsigned short At[2][BM * 32];
  __shared__ unsigned short Bt[2][BN * 32];

  const int t = threadIdx.x;
  const int lane = t & 63, wave = t >> 6;
  const int wm = wave >> 1, wn = wave & 1;            // 2x2 wave grid

  const unsigned short* Ab = A + (size_t)blockIdx.y * BM * lda;
  const unsigned short* Bb = B + (size_t)blockIdx.x * BN * ldb;

  const int frow = lane & 15, fk = (lane >> 4) << 3;

  f32x4 acc[TM][TN] = {};

  auto stage = [&](int ks, int bi) {
    const int k0 = ks << 5;
    #pragma unroll
    for (int r = 0; r < BM / 64; ++r) {
      int off16 = (r << 8) + t;
      int row = off16 >> 2, kk = (off16 & 3) << 3;
      gl_lds16(Ab + (size_t)row * lda + k0 + kk, &At[bi][(row << 5) + kk]);
    }
    #pragma unroll
    for (int r = 0; r < BN / 64; ++r) {
      int off16 = (r << 8) + t;
      int row = off16 >> 2, kk = (off16 & 3) << 3;
      gl_lds16(Bb + (size_t)row * ldb + k0 + kk, &Bt[bi][(row << 5) + kk]);
    }
  };

  stage(0, 0);

  for (int ks = 0; ks < kSteps; ++ks) {
    const int buf = ks & 1;
    __syncthreads();                        // drains prefetch for buf; prev reads done
    if (ks + 1 < kSteps) stage(ks + 1, buf ^ 1);

    bf16x8 af[TM], bv[TN];
    #pragma unroll
    for (int mi = 0; mi < TM; ++mi)
      af[mi] = *(const bf16x8*)&At[buf][((wm * (BM / 2) + mi * 16 + frow) << 5) + fk];
    #pragma unroll
    for (int ni = 0; ni < TN; ++ni)
      bv[ni] = *(const bf16x8*)&Bt[buf][((wn * (BN / 2) + ni * 16 + frow) << 5) + fk];
    #pragma unroll
    for (int mi = 0; mi < TM; ++mi)
      #pragma unroll
      for (int ni = 0; ni < TN; ++ni)
        acc[mi][ni] = __builtin_amdgcn_mfma_f32_16x16x32_bf16(af[mi], bv[ni], acc[mi][ni], 0, 0, 0);
  }

  // C/D layout (m89-verified): col = lane&15, row = (lane>>4)*4 + reg
  const int mb = blockIdx.y * BM + wm * (BM / 2) + ((lane >> 4) << 2);
  const int nb = blockIdx.x * BN + wn * (BN / 2) + (lane & 15);

  #pragma unroll
  for (int mi = 0; mi < TM; ++mi) {
    const int m = mb + mi * 16;
    #pragma unroll
    for (int ni = 0; ni < TN; ++ni) {
      const int n = nb + ni * 16;
      f32x4 v = acc[mi][ni];
      if constexpr (EPI == EPI_BIAS) {                 // bf16((acc + bias[n]) * scale)
        unsigned short* O = (unsigned short*)C0;
        const float bv2 = bias[n];
        #pragma unroll
        for (int r = 0; r < 4; ++r) O[(size_t)(m + r) * ldc + n] = f2bf((v[r] + bv2) * scale);
      } else if constexpr (EPI == EPI_VT) {            // V-proj -> Vt[b][h][d][li], +bias
        const int b = m / 576, li = m - b * 576;
        const int h = n >> 8, d = n & 255;
        const float bv2 = bias[n];
        ushort4 o;
        o.x = f2bf(v[0] + bv2); o.y = f2bf(v[1] + bv2);
        o.z = f2bf(v[2] + bv2); o.w = f2bf(v[3] + bv2);
        *(ushort4*)((unsigned short*)C0 + ((size_t)((b * 8 + h) * 256 + d)) * 576 + li) = o;
      } else if constexpr (EPI == EPI_DUAL) {          // out-proj: fp32 + bf16 copies
        float* Of = (float*)C0;
        unsigned short* Ob = (unsigned short*)C1;
        const float bv2 = bias[n];
        #pragma unroll
        for (int r = 0; r < 4; ++r) {
          const float x = v[r] + bv2;
          const size_t idx = (size_t)(m + r) * ldc + n;
          Of[idx] = x; Ob[idx] = f2bf(x);
        }
      } else if constexpr (EPI == EPI_RELU) {          // ff1: bf16(relu(acc+bias))
        unsigned short* O = (unsigned short*)C0;
        const float bv2 = bias[n];
        #pragma unroll
        for (int r = 0; r < 4; ++r) {
          const float x = v[r] + bv2;
          O[(size_t)(m + r) * ldc + n] = f2bf(x > 0.f ? x : 0.f);
        }
      } else if constexpr (EPI == EPI_RES) {           // ff2: fp32(acc+bias+resid)
        float* Of = (float*)C0;
        const float bv2 = bias[n];
        #pragma unroll
        for (int r = 0; r < 4; ++r) {
          const size_t idx = (size_t)(m + r) * ldc + n;
          Of[idx] = v[r] + bv2 + resid[idx];
        }
      }
    }
  }
}

// ---------- fused flash attention v4 ----------
// Q [8192][2048] bf16 (pre-scaled by log2(e)/16 => P = exp2(S), fixed-max
// softmax, no rescale). K [9216][2048] bf16, Vt [bh=128][d=256][li=576] bf16,
// X [8192][2048] bf16.
// Block 512 thr (8 waves), qtile 256 (32 q-rows/wave -> K/V LDS reads shared
// by 2 P-fragments: 35 reads / 66 MFMA per wave-step, 2x v3's ratio).
// Li-step 32, K/V double-buffered, ONE barrier per step. Grid 256 = 1/CU.
// l = rowsum via static ones-column d-tile. Ps padded to 40-short stride.
__global__ __launch_bounds__(512, 2)
void k_flash(const unsigned short* __restrict__ Q, const unsigned short* __restrict__ K,
             const unsigned short* __restrict__ Vt, unsigned short* __restrict__ X) {
  __shared__ unsigned short Ks[2][8 * 32 * 32];  // 16 KB x2  [kd8][li32][32]
  __shared__ unsigned short Vs[2][256 * 32];     // 16 KB x2  [d256][32li]
  __shared__ unsigned short Ps[256 * 40];        // 20 KB     [q256][li32] stride 40
  __shared__ unsigned short Ones[512];           //  1 KB     ones-column B-tile

  const int t = threadIdx.x, lane = t & 63, w = t >> 6;
  const int frow = lane & 15, quad = lane >> 4, fk = quad << 3;

  // XCD swizzle: id&7 = XCD; both q-blocks of one bh land on the same XCD
  const int id = blockIdx.x;
  const int qb = (id >> 3) & 1;
  const int bh = (id & 7) | ((id >> 4) << 3);
  const int b = bh >> 3, h = bh & 7;
  const int q0 = qb << 8;

  const unsigned short* Kg = K + ((size_t)b * 576) * 2048 + h * 256;
  const unsigned short* Vg = Vt + (size_t)bh * 147456;

  Ones[t] = (t < 32) ? (unsigned short)0x3F80 : (unsigned short)0;

  // Q fragments resident in VGPRs: wave w owns q rows q0+32w .. +31
  bf16x8 Qf[2][8];
  #pragma unroll
  for (int half = 0; half < 2; ++half) {
    const unsigned short* Qg =
        Q + ((size_t)(b * 512 + q0 + w * 32 + half * 16 + frow)) * 2048 + h * 256;
    #pragma unroll
    for (int kd = 0; kd < 8; ++kd)
      Qf[half][kd] = *(const bf16x8*)(Qg + kd * 32 + fk);
  }

  f32x4 acc_o[2][17] = {};   // [half][16 d-tiles + l]

  auto stage = [&](int s, int bi) {
    const int li0 = s << 5;
    unsigned short* Kb = &Ks[bi][0];
    unsigned short* Vb = &Vs[bi][0];
    #pragma unroll
    for (int it = 0; it < 2; ++it) {
      int e = (it << 9) + t;                    // 16B-chunk index, 0..1023
      int row = e >> 2, c = (e & 3) << 3;       // row = kd*32+li
      int kd = row >> 5, li = row & 31;
      gl_lds16(Kg + (size_t)(li0 + li) * 2048 + kd * 32 + c, &Kb[(row << 5) + c]);
    }
    #pragma unroll
    for (int it = 0; it < 2; ++it) {
      int e = (it << 9) + t;
      int d = e >> 2, c = (e & 3) << 3;
      gl_lds16(Vg + (size_t)d * 576 + li0 + c, &Vb[(d << 5) + c]);
    }
  };

  stage(0, 0);

  const int prow = (w << 5) + (quad << 2);     // Ps write row base (q within 256)

  for (int s = 0; s < 18; ++s) {
    const int buf = s & 1;
    __syncthreads();                 // drains vmcnt: buf(s) ready; prev consumed
    if (s + 1 < 18) stage(s + 1, buf ^ 1);

    // ---- S = Q_w @ K^T : 32 q x 32 li (K reads shared across halves) ----
    f32x4 acc_s[2][2] = {};
    #pragma unroll
    for (int kd = 0; kd < 8; ++kd) {
      #pragma unroll
      for (int ni = 0; ni < 2; ++ni) {
        const bf16x8 bv = *(const bf16x8*)&Ks[buf][((kd * 32 + ni * 16 + frow) << 5) + fk];
        acc_s[0][ni] = __builtin_amdgcn_mfma_f32_16x16x32_bf16(Qf[0][kd], bv, acc_s[0][ni], 0, 0, 0);
        acc_s[1][ni] = __builtin_amdgcn_mfma_f32_16x16x32_bf16(Qf[1][kd], bv, acc_s[1][ni], 0, 0, 0);
      }
    }

    // ---- P = exp2(S) (log2e folded into Q scale), write own Ps rows ----
    #pragma unroll
    for (int half = 0; half < 2; ++half)
      #pragma unroll
      for (int ni = 0; ni < 2; ++ni)
        #pragma unroll
        for (int r = 0; r < 4; ++r)
          Ps[(prow + half * 16 + r) * 40 + ni * 16 + frow] =
              f2bf(__builtin_amdgcn_exp2f(acc_s[half][ni][r]));

    // ---- O += P_w @ [V | 1]^T : 32q x 272d (V reads shared across halves) ----
    bf16x8 paf[2];
    paf[0] = *(const bf16x8*)&Ps[((w << 5) + frow) * 40 + fk];
    paf[1] = *(const bf16x8*)&Ps[((w << 5) + 16 + frow) * 40 + fk];
    #pragma unroll
    for (int ni = 0; ni < 16; ++ni) {
      const bf16x8 bv = *(const bf16x8*)&Vs[buf][((ni * 16 + frow) << 5) + fk];
      acc_o[0][ni] = __builtin_amdgcn_mfma_f32_16x16x32_bf16(paf[0], bv, acc_o[0][ni], 0, 0, 0);
      acc_o[1][ni] = __builtin_amdgcn_mfma_f32_16x16x32_bf16(paf[1], bv, acc_o[1][ni], 0, 0, 0);
    }
    {
      const bf16x8 bv = *(const bf16x8*)&Ones[(frow << 5) + fk];
      acc_o[0][16] = __builtin_amdgcn_mfma_f32_16x16x32_bf16(paf[0], bv, acc_o[0][16], 0, 0, 0);
      acc_o[1][16] = __builtin_amdgcn_mfma_f32_16x16x32_bf16(paf[1], bv, acc_o[1][16], 0, 0, 0);
    }
  }

  // ---- epilogue: l in acc_o[half][16] on lanes frow==0; broadcast in-quad ----
  #pragma unroll
  for (int half = 0; half < 2; ++half) {
    float linv[4];
    #pragma unroll
    for (int r = 0; r < 4; ++r)
      linv[r] = 1.0f / __shfl(acc_o[half][16][r], lane & 48);
    unsigned short* Xo = X + ((size_t)(b * 512 + q0 + w * 32 + half * 16 + (quad << 2))) * 2048 +
                         h * 256 + frow;
    #pragma unroll
    for (int ni = 0; ni < 16; ++ni)
      #pragma unroll
      for (int r = 0; r < 4; ++r)
        Xo[(size_t)r * 2048 + ni * 16] = f2bf(acc_o[half][ni][r] * linv[r]);
  }
}

// ---------- LayerNorm over 768, in place on fp32 rows ----------
__global__ __launch_bounds__(256) void k_layernorm768(float* O, const float* __restrict__ gamma,
                                                      const float* __restrict__ beta) {
  const int row = blockIdx.x;
  float* p = O + (size_t)row * 768;
  const int t = threadIdx.x;
  const int lane = t & 63, wave = t >> 6;
  const float x0 = p[t], x1 = p[t + 256], x2 = p[t + 512];
  float s = x0 + x1 + x2;
  float q = x0 * x0 + x1 * x1 + x2 * x2;
  #pragma unroll
  for (int i = 32; i >= 1; i >>= 1) { s += __shfl_xor(s, i); q += __shfl_xor(q, i); }
  __shared__ float rs[4], rq[4];
  if (lane == 0) { rs[wave] = s; rq[wave] = q; }
  __syncthreads();
  s = rs[0] + rs[1] + rs[2] + rs[3];
  q = rq[0] + rq[1] + rq[2] + rq[3];
  const float mu = s * (1.0f / 768.0f);
  const float var = q * (1.0f / 768.0f) - mu * mu;
  const float inv = rsqrtf(var + 1e-5f);
  p[t]       = (x0 - mu) * inv * gamma[t]       + beta[t];
  p[t + 256] = (x1 - mu) * inv * gamma[t + 256] + beta[t + 256];
  p[t + 512] = (x2 - mu) * inv * gamma[t + 512] + beta[t + 512];
}

// ---------- host ----------
extern "C" void kernel_launch(void* const* d_in, const int* in_sizes, int n_in,
                              void* d_out, int out_size, void* d_ws, size_t ws_size,
                              hipStream_t stream) {
  const float* text  = (const float*)d_in[0];
  const float* image = (const float*)d_in[1];
  const float* wq = (const float*)d_in[2];  const float* bq = (const float*)d_in[3];
  const float* wk = (const float*)d_in[4];  const float* bk = (const float*)d_in[5];
  const float* wv = (const float*)d_in[6];  const float* bv = (const float*)d_in[7];
  const float* wr = (const float*)d_in[8];  const float* br = (const float*)d_in[9];
  const float* w1 = (const float*)d_in[10]; const float* b1 = (const float*)d_in[11];
  const float* w2 = (const float*)d_in[12]; const float* b2 = (const float*)d_in[13];
  const float* gamma = (const float*)d_in[14]; const float* beta = (const float*)d_in[15];

  uint8_t* ws = (uint8_t*)d_ws;
  constexpr size_t o_Tbf = 0;
  constexpr size_t o_Ibf = 12582912;                 // 8192*768*2
  constexpr size_t o_X   = 0;                        // reuse region0 (disjoint lifetime)
  constexpr size_t o_Q   = 33554432;
  constexpr size_t o_Kb  = o_Q   + 33554432;         // 8192*2048*2
  constexpr size_t o_Vt  = o_Kb  + 37748736;         // 9216*2048*2
  constexpr size_t o_wqT = o_Vt  + 37748736;
  constexpr size_t o_wkT = o_wqT + 3145728;
  constexpr size_t o_wvT = o_wkT + 4194304;
  constexpr size_t o_wrT = o_wvT + 4194304;
  constexpr size_t o_w1T = o_wrT + 3145728;
  constexpr size_t o_w2T = o_w1T + 196608;
  constexpr size_t o_OutB= o_w2T + 196608;
  constexpr size_t o_H   = o_OutB+ 12582912;         // 8192*768*2

  unsigned short* Tbf  = (unsigned short*)(ws + o_Tbf);
  unsigned short* Ibf  = (unsigned short*)(ws + o_Ibf);
  unsigned short* Xb   = (unsigned short*)(ws + o_X);
  unsigned short* Qb   = (unsigned short*)(ws + o_Q);
  unsigned short* Kb   = (unsigned short*)(ws + o_Kb);
  unsigned short* Vt   = (unsigned short*)(ws + o_Vt);
  unsigned short* wqT  = (unsigned short*)(ws + o_wqT);
  unsigned short* wkT  = (unsigned short*)(ws + o_wkT);
  unsigned short* wvT  = (unsigned short*)(ws + o_wvT);
  unsigned short* wrT  = (unsigned short*)(ws + o_wrT);
  unsigned short* w1T  = (unsigned short*)(ws + o_w1T);
  unsigned short* w2T  = (unsigned short*)(ws + o_w2T);
  unsigned short* OutB = (unsigned short*)(ws + o_OutB);
  unsigned short* Hb   = (unsigned short*)(ws + o_H);
  float* OutF = (float*)d_out;

  const dim3 blk(256);

  // --- prep: convert inputs, transpose weights (fp32 -> bf16) ---
  k_f32_to_bf16<<<dim3(6144), blk, 0, stream>>>(text,  Tbf, 1572864);
  k_f32_to_bf16<<<dim3(9216), blk, 0, stream>>>(image, Ibf, 2359296);
  k_transpose_to_bf16<<<dim3(64, 24), blk, 0, stream>>>(wq, wqT, 768, 2048);
  k_transpose_to_bf16<<<dim3(64, 32), blk, 0, stream>>>(wk, wkT, 1024, 2048);
  k_transpose_to_bf16<<<dim3(64, 32), blk, 0, stream>>>(wv, wvT, 1024, 2048);
  k_transpose_to_bf16<<<dim3(24, 64), blk, 0, stream>>>(wr, wrT, 2048, 768);
  k_transpose_to_bf16<<<dim3(4, 24),  blk, 0, stream>>>(w1, w1T, 768, 128);
  k_transpose_to_bf16<<<dim3(24, 4),  blk, 0, stream>>>(w2, w2T, 128, 768);

  // --- Q = (text @ wq + bq) * log2(e)/16 (attn scale + exp2 conversion) ---
  // 256x128 tiles: M=8192 -> 32 row-blocks, N=2048 -> 16 col-blocks
  k_gemm<256, 128, EPI_BIAS><<<dim3(16, 32), blk, 0, stream>>>(
      Tbf, wqT, 768, 768, 24, Qb, nullptr, bq, nullptr, 2048, 0.0625f * 1.44269504f);
  // --- K = image @ wk + bk : M=9216 -> 36 row-blocks ---
  k_gemm<256, 128, EPI_BIAS><<<dim3(16, 36), blk, 0, stream>>>(
      Ibf, wkT, 1024, 1024, 32, Kb, nullptr, bk, nullptr, 2048, 1.0f);
  // --- V = image @ wv + bv, written transposed as Vt[b][h][d][li] ---
  k_gemm<256, 128, EPI_VT><<<dim3(16, 36), blk, 0, stream>>>(
      Ibf, wvT, 1024, 1024, 32, Vt, nullptr, bv, nullptr, 0, 1.0f);

  // --- fused attention: X = softmax(QK^T)V ---
  k_flash<<<dim3(256), dim3(512), 0, stream>>>(Qb, Kb, Vt, Xb);

  // --- out = X @ wr + br : fp32 into d_out + bf16 copy for FF ---
  k_gemm<256, 128, EPI_DUAL><<<dim3(6, 32), blk, 0, stream>>>(
      Xb, wrT, 2048, 2048, 64, OutF, OutB, br, nullptr, 768, 1.0f);

  // --- h = relu(out @ w1 + b1) : [8192,128], 64x64 tiles for 256 blocks ---
  k_gemm<64, 64, EPI_RELU><<<dim3(2, 128), blk, 0, stream>>>(
      OutB, w1T, 768, 768, 24, Hb, nullptr, b1, nullptr, 128, 1.0f);

  // --- out += h @ w2 + b2 (residual from d_out) ---
  k_gemm<128, 128, EPI_RES><<<dim3(6, 64), blk, 0, stream>>>(
      Hb, w2T, 128, 128, 4, OutF, nullptr, b2, (const float*)d_out, 768, 1.0f);

  // --- LayerNorm in place on d_out ---
  k_layernorm768<<<dim3(8192), blk, 0, stream>>>(OutF, gamma, beta);

  (void)in_sizes; (void)n_in; (void)out_size; (void)ws_size;
}

// Round 2
// 488.976 us; speedup vs baseline: 1.0708x; 1.0708x over previous
//
#include <hip/hip_runtime.h>
#include <stdint.h>
#include <stddef.h>

// ---------- types / helpers ----------
typedef __attribute__((ext_vector_type(8))) short bf16x8;   // 8 bf16 in 4 VGPRs
typedef __attribute__((ext_vector_type(4))) float f32x4;

typedef __attribute__((address_space(1))) unsigned int uint_g;
typedef __attribute__((address_space(3))) unsigned int uint_l;

#define DEV static __device__ __forceinline__

DEV unsigned short f2bf(float f) {          // RNE float -> bf16 bits
  unsigned int u = __float_as_uint(f);
  u += 0x7FFFu + ((u >> 16) & 1u);
  return (unsigned short)(u >> 16);
}

DEV void gl_lds16(const unsigned short* g, unsigned short* l) {
  // async global->LDS, 16B per lane; LDS dest = wave-uniform base + lane*16
  __builtin_amdgcn_global_load_lds((const uint_g*)g, (uint_l*)l, 16, 0, 0);
}

// ---------- elementwise f32 -> bf16 (vectorized x4) ----------
__global__ __launch_bounds__(256) void k_f32_to_bf16(const float* __restrict__ in,
                                                     unsigned short* __restrict__ out, int n4) {
  int i = blockIdx.x * 256 + threadIdx.x;
  if (i >= n4) return;
  const float4 v = ((const float4*)in)[i];
  ushort4 o;
  o.x = f2bf(v.x); o.y = f2bf(v.y); o.z = f2bf(v.z); o.w = f2bf(v.w);
  ((ushort4*)out)[i] = o;
}

// ---------- transpose fp32 [R][C] -> bf16 [C][R] ----------
__global__ __launch_bounds__(256) void k_transpose_to_bf16(const float* __restrict__ in,
                                                           unsigned short* __restrict__ out,
                                                           int R, int C) {
  __shared__ unsigned short tile[32][33];   // +1 pad breaks bank conflicts
  const int c0 = blockIdx.x << 5, r0 = blockIdx.y << 5;
  const int tx = threadIdx.x & 31, ty = threadIdx.x >> 5;   // 32x8
  #pragma unroll
  for (int i = 0; i < 32; i += 8)
    tile[ty + i][tx] = f2bf(in[(size_t)(r0 + ty + i) * C + c0 + tx]);
  __syncthreads();
  #pragma unroll
  for (int i = 0; i < 32; i += 8)
    out[(size_t)(c0 + ty + i) * R + r0 + tx] = tile[tx][ty + i];
}

// ---------- generic bf16 MFMA GEMM: C = A @ B^T (+epilogue) ----------
// v4: round-0 geometry (128x128 / 64x64, 4 waves, BK=32, single-barrier
// double-buffer) + two changes:
//  (a) __launch_bounds__(256,4): force <=128 total regs (64 VGPR + 64 AGPR
//      acc) -> 4 waves/SIMD -> 4 blocks/CU co-resident. The per-step
//      vmcnt(0)+barrier drain (m233: ~72% of the 2-phase critical path) is
//      hidden only by OTHER resident blocks (m114); round-1 proved fewer
//      blocks = slower.
//  (b) XCD swizzle (T1): launch-id%8 = XCD; give each XCD a contiguous
//      logical-block chunk so its A-panels fit L2 (default round-robin
//      thrashes all 72 A-panels through one 4MB L2 -> 3.4x HBM over-fetch).
enum { EPI_BIAS = 0, EPI_VT = 3, EPI_DUAL = 4, EPI_RELU = 5, EPI_RES = 6 };

template <int BM, int BN, int EPI>
__global__ __launch_bounds__(256, 4)
void k_gemm(const unsigned short* __restrict__ A, const unsigned short* __restrict__ B,
            int lda, int ldb, int kSteps,
            void* C0, void* C1, const float* bias, const float* resid, int ldc, float scale) {
  constexpr int TM = BM / 32;
  constexpr int TN = BN / 32;
  __shared__ unsigned short At[2][BM * 32];
  __shared__ unsigned short Bt[2][BN * 32];

  const int t = threadIdx.x;
  const int lane = t & 63, wave = t >> 6;
  const int wm = wave >> 1, wn = wave & 1;            // 2x2 wave grid

  // T1 XCD swizzle: launch id -> logical work id. All grids are %8==0.
  const int gx = gridDim.x;
  const int nwg = gx * gridDim.y;
  const int fid = blockIdx.y * gx + blockIdx.x;       // physical launch id
  const int nid = (fid & 7) * (nwg >> 3) + (fid >> 3); // logical work id
  const int by = nid / gx;
  const int bx = nid - by * gx;

  const unsigned short* Ab = A + (size_t)by * BM * lda;
  const unsigned short* Bb = B + (size_t)bx * BN * ldb;

  const int frow = lane & 15, fk = (lane >> 4) << 3;

  f32x4 acc[TM][TN] = {};

  auto stage = [&](int ks, int bi) {
    const int k0 = ks << 5;
    #pragma unroll
    for (int r = 0; r < BM / 64; ++r) {
      int off16 = (r << 8) + t;
      int row = off16 >> 2, kk = (off16 & 3) << 3;
      gl_lds16(Ab + (size_t)row * lda + k0 + kk, &At[bi][(row << 5) + kk]);
    }
    #pragma unroll
    for (int r = 0; r < BN / 64; ++r) {
      int off16 = (r << 8) + t;
      int row = off16 >> 2, kk = (off16 & 3) << 3;
      gl_lds16(Bb + (size_t)row * ldb + k0 + kk, &Bt[bi][(row << 5) + kk]);
    }
  };

  stage(0, 0);

  for (int ks = 0; ks < kSteps; ++ks) {
    const int buf = ks & 1;
    __syncthreads();                        // drains prefetch for buf; prev reads done
    if (ks + 1 < kSteps) stage(ks + 1, buf ^ 1);

    bf16x8 af[TM], bv[TN];
    #pragma unroll
    for (int mi = 0; mi < TM; ++mi)
      af[mi] = *(const bf16x8*)&At[buf][((wm * (BM / 2) + mi * 16 + frow) << 5) + fk];
    #pragma unroll
    for (int ni = 0; ni < TN; ++ni)
      bv[ni] = *(const bf16x8*)&Bt[buf][((wn * (BN / 2) + ni * 16 + frow) << 5) + fk];
    #pragma unroll
    for (int mi = 0; mi < TM; ++mi)
      #pragma unroll
      for (int ni = 0; ni < TN; ++ni)
        acc[mi][ni] = __builtin_amdgcn_mfma_f32_16x16x32_bf16(af[mi], bv[ni], acc[mi][ni], 0, 0, 0);
  }

  // C/D layout (m89-verified): col = lane&15, row = (lane>>4)*4 + reg
  const int mb = by * BM + wm * (BM / 2) + ((lane >> 4) << 2);
  const int nb = bx * BN + wn * (BN / 2) + (lane & 15);

  #pragma unroll
  for (int mi = 0; mi < TM; ++mi) {
    const int m = mb + mi * 16;
    #pragma unroll
    for (int ni = 0; ni < TN; ++ni) {
      const int n = nb + ni * 16;
      f32x4 v = acc[mi][ni];
      if constexpr (EPI == EPI_BIAS) {                 // bf16((acc + bias[n]) * scale)
        unsigned short* O = (unsigned short*)C0;
        const float bv2 = bias[n];
        #pragma unroll
        for (int r = 0; r < 4; ++r) O[(size_t)(m + r) * ldc + n] = f2bf((v[r] + bv2) * scale);
      } else if constexpr (EPI == EPI_VT) {            // V-proj -> Vt[b][h][d][li], +bias
        const int b = m / 576, li = m - b * 576;
        const int h = n >> 8, d = n & 255;
        const float bv2 = bias[n];
        ushort4 o;
        o.x = f2bf(v[0] + bv2); o.y = f2bf(v[1] + bv2);
        o.z = f2bf(v[2] + bv2); o.w = f2bf(v[3] + bv2);
        *(ushort4*)((unsigned short*)C0 + ((size_t)((b * 8 + h) * 256 + d)) * 576 + li) = o;
      } else if constexpr (EPI == EPI_DUAL) {          // out-proj: fp32 + bf16 copies
        float* Of = (float*)C0;
        unsigned short* Ob = (unsigned short*)C1;
        const float bv2 = bias[n];
        #pragma unroll
        for (int r = 0; r < 4; ++r) {
          const float x = v[r] + bv2;
          const size_t idx = (size_t)(m + r) * ldc + n;
          Of[idx] = x; Ob[idx] = f2bf(x);
        }
      } else if constexpr (EPI == EPI_RELU) {          // ff1: bf16(relu(acc+bias))
        unsigned short* O = (unsigned short*)C0;
        const float bv2 = bias[n];
        #pragma unroll
        for (int r = 0; r < 4; ++r) {
          const float x = v[r] + bv2;
          O[(size_t)(m + r) * ldc + n] = f2bf(x > 0.f ? x : 0.f);
        }
      } else if constexpr (EPI == EPI_RES) {           // ff2: fp32(acc+bias+resid)
        float* Of = (float*)C0;
        const float bv2 = bias[n];
        #pragma unroll
        for (int r = 0; r < 4; ++r) {
          const size_t idx = (size_t)(m + r) * ldc + n;
          Of[idx] = v[r] + bv2 + resid[idx];
        }
      }
    }
  }
}

// ---------- fused flash attention v4 ----------
// Q [8192][2048] bf16 (pre-scaled by log2(e)/16 => P = exp2(S), fixed-max
// softmax, no rescale). K [9216][2048] bf16, Vt [bh=128][d=256][li=576] bf16,
// X [8192][2048] bf16.
// Block 512 thr (8 waves), qtile 256 (32 q-rows/wave -> K/V LDS reads shared
// by 2 P-fragments: 35 reads / 66 MFMA per wave-step, 2x v3's ratio).
// Li-step 32, K/V double-buffered, ONE barrier per step. Grid 256 = 1/CU.
// l = rowsum via static ones-column d-tile. Ps padded to 40-short stride.
__global__ __launch_bounds__(512, 2)
void k_flash(const unsigned short* __restrict__ Q, const unsigned short* __restrict__ K,
             const unsigned short* __restrict__ Vt, unsigned short* __restrict__ X) {
  __shared__ unsigned short Ks[2][8 * 32 * 32];  // 16 KB x2  [kd8][li32][32]
  __shared__ unsigned short Vs[2][256 * 32];     // 16 KB x2  [d256][32li]
  __shared__ unsigned short Ps[256 * 40];        // 20 KB     [q256][li32] stride 40
  __shared__ unsigned short Ones[512];           //  1 KB     ones-column B-tile

  const int t = threadIdx.x, lane = t & 63, w = t >> 6;
  const int frow = lane & 15, quad = lane >> 4, fk = quad << 3;

  // XCD swizzle: id&7 = XCD; both q-blocks of one bh land on the same XCD
  const int id = blockIdx.x;
  const int qb = (id >> 3) & 1;
  const int bh = (id & 7) | ((id >> 4) << 3);
  const int b = bh >> 3, h = bh & 7;
  const int q0 = qb << 8;

  const unsigned short* Kg = K + ((size_t)b * 576) * 2048 + h * 256;
  const unsigned short* Vg = Vt + (size_t)bh * 147456;

  Ones[t] = (t < 32) ? (unsigned short)0x3F80 : (unsigned short)0;

  // Q fragments resident in VGPRs: wave w owns q rows q0+32w .. +31
  bf16x8 Qf[2][8];
  #pragma unroll
  for (int half = 0; half < 2; ++half) {
    const unsigned short* Qg =
        Q + ((size_t)(b * 512 + q0 + w * 32 + half * 16 + frow)) * 2048 + h * 256;
    #pragma unroll
    for (int kd = 0; kd < 8; ++kd)
      Qf[half][kd] = *(const bf16x8*)(Qg + kd * 32 + fk);
  }

  f32x4 acc_o[2][17] = {};   // [half][16 d-tiles + l]

  auto stage = [&](int s, int bi) {
    const int li0 = s << 5;
    unsigned short* Kb = &Ks[bi][0];
    unsigned short* Vb = &Vs[bi][0];
    #pragma unroll
    for (int it = 0; it < 2; ++it) {
      int e = (it << 9) + t;                    // 16B-chunk index, 0..1023
      int row = e >> 2, c = (e & 3) << 3;       // row = kd*32+li
      int kd = row >> 5, li = row & 31;
      gl_lds16(Kg + (size_t)(li0 + li) * 2048 + kd * 32 + c, &Kb[(row << 5) + c]);
    }
    #pragma unroll
    for (int it = 0; it < 2; ++it) {
      int e = (it << 9) + t;
      int d = e >> 2, c = (e & 3) << 3;
      gl_lds16(Vg + (size_t)d * 576 + li0 + c, &Vb[(d << 5) + c]);
    }
  };

  stage(0, 0);

  const int prow = (w << 5) + (quad << 2);     // Ps write row base (q within 256)

  for (int s = 0; s < 18; ++s) {
    const int buf = s & 1;
    __syncthreads();                 // drains vmcnt: buf(s) ready; prev consumed
    if (s + 1 < 18) stage(s + 1, buf ^ 1);

    // ---- S = Q_w @ K^T : 32 q x 32 li (K reads shared across halves) ----
    f32x4 acc_s[2][2] = {};
    #pragma unroll
    for (int kd = 0; kd < 8; ++kd) {
      #pragma unroll
      for (int ni = 0; ni < 2; ++ni) {
        const bf16x8 bv = *(const bf16x8*)&Ks[buf][((kd * 32 + ni * 16 + frow) << 5) + fk];
        acc_s[0][ni] = __builtin_amdgcn_mfma_f32_16x16x32_bf16(Qf[0][kd], bv, acc_s[0][ni], 0, 0, 0);
        acc_s[1][ni] = __builtin_amdgcn_mfma_f32_16x16x32_bf16(Qf[1][kd], bv, acc_s[1][ni], 0, 0, 0);
      }
    }

    // ---- P = exp2(S) (log2e folded into Q scale), write own Ps rows ----
    #pragma unroll
    for (int half = 0; half < 2; ++half)
      #pragma unroll
      for (int ni = 0; ni < 2; ++ni)
        #pragma unroll
        for (int r = 0; r < 4; ++r)
          Ps[(prow + half * 16 + r) * 40 + ni * 16 + frow] =
              f2bf(__builtin_amdgcn_exp2f(acc_s[half][ni][r]));

    // ---- O += P_w @ [V | 1]^T : 32q x 272d (V reads shared across halves) ----
    bf16x8 paf[2];
    paf[0] = *(const bf16x8*)&Ps[((w << 5) + frow) * 40 + fk];
    paf[1] = *(const bf16x8*)&Ps[((w << 5) + 16 + frow) * 40 + fk];
    #pragma unroll
    for (int ni = 0; ni < 16; ++ni) {
      const bf16x8 bv = *(const bf16x8*)&Vs[buf][((ni * 16 + frow) << 5) + fk];
      acc_o[0][ni] = __builtin_amdgcn_mfma_f32_16x16x32_bf16(paf[0], bv, acc_o[0][ni], 0, 0, 0);
      acc_o[1][ni] = __builtin_amdgcn_mfma_f32_16x16x32_bf16(paf[1], bv, acc_o[1][ni], 0, 0, 0);
    }
    {
      const bf16x8 bv = *(const bf16x8*)&Ones[(frow << 5) + fk];
      acc_o[0][16] = __builtin_amdgcn_mfma_f32_16x16x32_bf16(paf[0], bv, acc_o[0][16], 0, 0, 0);
      acc_o[1][16] = __builtin_amdgcn_mfma_f32_16x16x32_bf16(paf[1], bv, acc_o[1][16], 0, 0, 0);
    }
  }

  // ---- epilogue: l in acc_o[half][16] on lanes frow==0; broadcast in-quad ----
  #pragma unroll
  for (int half = 0; half < 2; ++half) {
    float linv[4];
    #pragma unroll
    for (int r = 0; r < 4; ++r)
      linv[r] = 1.0f / __shfl(acc_o[half][16][r], lane & 48);
    unsigned short* Xo = X + ((size_t)(b * 512 + q0 + w * 32 + half * 16 + (quad << 2))) * 2048 +
                         h * 256 + frow;
    #pragma unroll
    for (int ni = 0; ni < 16; ++ni)
      #pragma unroll
      for (int r = 0; r < 4; ++r)
        Xo[(size_t)r * 2048 + ni * 16] = f2bf(acc_o[half][ni][r] * linv[r]);
  }
}

// ---------- LayerNorm over 768, in place on fp32 rows ----------
__global__ __launch_bounds__(256) void k_layernorm768(float* O, const float* __restrict__ gamma,
                                                      const float* __restrict__ beta) {
  const int row = blockIdx.x;
  float* p = O + (size_t)row * 768;
  const int t = threadIdx.x;
  const int lane = t & 63, wave = t >> 6;
  const float x0 = p[t], x1 = p[t + 256], x2 = p[t + 512];
  float s = x0 + x1 + x2;
  float q = x0 * x0 + x1 * x1 + x2 * x2;
  #pragma unroll
  for (int i = 32; i >= 1; i >>= 1) { s += __shfl_xor(s, i); q += __shfl_xor(q, i); }
  __shared__ float rs[4], rq[4];
  if (lane == 0) { rs[wave] = s; rq[wave] = q; }
  __syncthreads();
  s = rs[0] + rs[1] + rs[2] + rs[3];
  q = rq[0] + rq[1] + rq[2] + rq[3];
  const float mu = s * (1.0f / 768.0f);
  const float var = q * (1.0f / 768.0f) - mu * mu;
  const float inv = rsqrtf(var + 1e-5f);
  p[t]       = (x0 - mu) * inv * gamma[t]       + beta[t];
  p[t + 256] = (x1 - mu) * inv * gamma[t + 256] + beta[t + 256];
  p[t + 512] = (x2 - mu) * inv * gamma[t + 512] + beta[t + 512];
}

// ---------- host ----------
extern "C" void kernel_launch(void* const* d_in, const int* in_sizes, int n_in,
                              void* d_out, int out_size, void* d_ws, size_t ws_size,
                              hipStream_t stream) {
  const float* text  = (const float*)d_in[0];
  const float* image = (const float*)d_in[1];
  const float* wq = (const float*)d_in[2];  const float* bq = (const float*)d_in[3];
  const float* wk = (const float*)d_in[4];  const float* bk = (const float*)d_in[5];
  const float* wv = (const float*)d_in[6];  const float* bv = (const float*)d_in[7];
  const float* wr = (const float*)d_in[8];  const float* br = (const float*)d_in[9];
  const float* w1 = (const float*)d_in[10]; const float* b1 = (const float*)d_in[11];
  const float* w2 = (const float*)d_in[12]; const float* b2 = (const float*)d_in[13];
  const float* gamma = (const float*)d_in[14]; const float* beta = (const float*)d_in[15];

  uint8_t* ws = (uint8_t*)d_ws;
  constexpr size_t o_Tbf = 0;
  constexpr size_t o_Ibf = 12582912;                 // 8192*768*2
  constexpr size_t o_X   = 0;                        // reuse region0 (disjoint lifetime)
  constexpr size_t o_Q   = 33554432;
  constexpr size_t o_Kb  = o_Q   + 33554432;         // 8192*2048*2
  constexpr size_t o_Vt  = o_Kb  + 37748736;         // 9216*2048*2
  constexpr size_t o_wqT = o_Vt  + 37748736;
  constexpr size_t o_wkT = o_wqT + 3145728;
  constexpr size_t o_wvT = o_wkT + 4194304;
  constexpr size_t o_wrT = o_wvT + 4194304;
  constexpr size_t o_w1T = o_wrT + 3145728;
  constexpr size_t o_w2T = o_w1T + 196608;
  constexpr size_t o_OutB= o_w2T + 196608;
  constexpr size_t o_H   = o_OutB+ 12582912;         // 8192*768*2

  unsigned short* Tbf  = (unsigned short*)(ws + o_Tbf);
  unsigned short* Ibf  = (unsigned short*)(ws + o_Ibf);
  unsigned short* Xb   = (unsigned short*)(ws + o_X);
  unsigned short* Qb   = (unsigned short*)(ws + o_Q);
  unsigned short* Kb   = (unsigned short*)(ws + o_Kb);
  unsigned short* Vt   = (unsigned short*)(ws + o_Vt);
  unsigned short* wqT  = (unsigned short*)(ws + o_wqT);
  unsigned short* wkT  = (unsigned short*)(ws + o_wkT);
  unsigned short* wvT  = (unsigned short*)(ws + o_wvT);
  unsigned short* wrT  = (unsigned short*)(ws + o_wrT);
  unsigned short* w1T  = (unsigned short*)(ws + o_w1T);
  unsigned short* w2T  = (unsigned short*)(ws + o_w2T);
  unsigned short* OutB = (unsigned short*)(ws + o_OutB);
  unsigned short* Hb   = (unsigned short*)(ws + o_H);
  float* OutF = (float*)d_out;

  const dim3 blk(256);

  // --- prep: convert inputs, transpose weights (fp32 -> bf16) ---
  k_f32_to_bf16<<<dim3(6144), blk, 0, stream>>>(text,  Tbf, 1572864);
  k_f32_to_bf16<<<dim3(9216), blk, 0, stream>>>(image, Ibf, 2359296);
  k_transpose_to_bf16<<<dim3(64, 24), blk, 0, stream>>>(wq, wqT, 768, 2048);
  k_transpose_to_bf16<<<dim3(64, 32), blk, 0, stream>>>(wk, wkT, 1024, 2048);
  k_transpose_to_bf16<<<dim3(64, 32), blk, 0, stream>>>(wv, wvT, 1024, 2048);
  k_transpose_to_bf16<<<dim3(24, 64), blk, 0, stream>>>(wr, wrT, 2048, 768);
  k_transpose_to_bf16<<<dim3(4, 24),  blk, 0, stream>>>(w1, w1T, 768, 128);
  k_transpose_to_bf16<<<dim3(24, 4),  blk, 0, stream>>>(w2, w2T, 128, 768);

  // --- Q = (text @ wq + bq) * log2(e)/16 (attn scale + exp2 conversion) ---
  k_gemm<128, 128, EPI_BIAS><<<dim3(16, 64), blk, 0, stream>>>(
      Tbf, wqT, 768, 768, 24, Qb, nullptr, bq, nullptr, 2048, 0.0625f * 1.44269504f);
  // --- K = image @ wk + bk ---
  k_gemm<128, 128, EPI_BIAS><<<dim3(16, 72), blk, 0, stream>>>(
      Ibf, wkT, 1024, 1024, 32, Kb, nullptr, bk, nullptr, 2048, 1.0f);
  // --- V = image @ wv + bv, written transposed as Vt[b][h][d][li] ---
  k_gemm<128, 128, EPI_VT><<<dim3(16, 72), blk, 0, stream>>>(
      Ibf, wvT, 1024, 1024, 32, Vt, nullptr, bv, nullptr, 0, 1.0f);

  // --- fused attention: X = softmax(QK^T)V ---
  k_flash<<<dim3(256), dim3(512), 0, stream>>>(Qb, Kb, Vt, Xb);

  // --- out = X @ wr + br : fp32 into d_out + bf16 copy for FF ---
  k_gemm<128, 128, EPI_DUAL><<<dim3(6, 64), blk, 0, stream>>>(
      Xb, wrT, 2048, 2048, 64, OutF, OutB, br, nullptr, 768, 1.0f);

  // --- h = relu(out @ w1 + b1) : [8192,128], 64x64 tiles for 256 blocks ---
  k_gemm<64, 64, EPI_RELU><<<dim3(2, 128), blk, 0, stream>>>(
      OutB, w1T, 768, 768, 24, Hb, nullptr, b1, nullptr, 128, 1.0f);

  // --- out += h @ w2 + b2 (residual from d_out) ---
  k_gemm<128, 128, EPI_RES><<<dim3(6, 64), blk, 0, stream>>>(
      Hb, w2T, 128, 128, 4, OutF, nullptr, b2, (const float*)d_out, 768, 1.0f);

  // --- LayerNorm in place on d_out ---
  k_layernorm768<<<dim3(8192), blk, 0, stream>>>(OutF, gamma, beta);

  (void)in_sizes; (void)n_in; (void)out_size; (void)ws_size;
}